// Round 12
// baseline (259.361 us; speedup 1.0000x reference)
//
#include <hip/hip_runtime.h>
#include <math.h>

#define HID 128
#define POOL_S 8
#define BSH 6        // nodes per bucket = 64
#define BCAP 2048    // bucket capacity (mean ~1024 at E=800K, NB=782)

typedef __attribute__((ext_vector_type(8))) short bf16x8;
typedef __attribute__((ext_vector_type(4))) float f32x4;

static __device__ __forceinline__ float eluf(float x){ return x > 0.f ? x : expm1f(x); }

// round-to-nearest-even f32 -> bf16 bits
static __device__ __forceinline__ unsigned short f2bf(float f){
  unsigned u = __builtin_bit_cast(unsigned, f);
  u += 0x7fffu + ((u >> 16) & 1u);
  return (unsigned short)(u >> 16);
}
static __device__ __forceinline__ float bf2f(unsigned short h){
  return __builtin_bit_cast(float, (unsigned)h << 16);
}
static __device__ __forceinline__ float bflo(unsigned u){ return __builtin_bit_cast(float, u << 16); }
static __device__ __forceinline__ float bfhi(unsigned u){ return __builtin_bit_cast(float, u & 0xffff0000u); }
static __device__ __forceinline__ unsigned packbf(float a, float b){
  return (unsigned)f2bf(a) | ((unsigned)f2bf(b) << 16);
}

// pass 1: bucket edges by dst>>BSH; entry = (d<<16)|s  (N < 65536)
__global__ __launch_bounds__(256) void k_bucket(const int* __restrict__ src, const int* __restrict__ dst,
    int* __restrict__ bcnt, unsigned* __restrict__ bedges, int E, int NB){
  __shared__ int hist[1024];
  __shared__ int base[1024];
  int t = threadIdx.x;
  int e0 = blockIdx.x * 2048;
  int e1 = min(e0 + 2048, E);
  for (int i=t;i<NB;i+=256) hist[i]=0;
  __syncthreads();
  for (int e=e0+t; e<e1; e+=256) atomicAdd(&hist[dst[e]>>BSH],1);
  __syncthreads();
  for (int i=t;i<NB;i+=256){
    int c = hist[i];
    base[i] = (c>0) ? atomicAdd(&bcnt[i], c) : 0;
    hist[i] = 0;   // reuse as local cursor
  }
  __syncthreads();
  for (int e=e0+t; e<e1; e+=256){
    int d = dst[e], s = src[e];
    int b = d>>BSH;
    int off = base[b] + atomicAdd(&hist[b],1);
    if (off < BCAP)
      bedges[(size_t)b*BCAP + off] = ((unsigned)d << 16) | (unsigned)s;
  }
}

// exclusive scan of bcnt (NB <= 1024) in one block
__global__ __launch_bounds__(1024) void k_scan_bcnt(const int* __restrict__ bcnt,
                                                    int* __restrict__ bbase, int NB){
  __shared__ int ts[1024];
  int t = threadIdx.x;
  int v = (t<NB) ? bcnt[t] : 0;
  ts[t]=v; __syncthreads();
  for (int off=1; off<1024; off<<=1){
    int x = (t>=off)?ts[t-off]:0; __syncthreads();
    ts[t]+=x; __syncthreads();
  }
  if (t<NB) bbase[t] = ts[t]-v;
}

// pass 2: per bucket: LDS count -> deg/dinv/rowptr, then scatter packed entries
__global__ __launch_bounds__(256) void k_csr(const unsigned* __restrict__ bedges,
    const int* __restrict__ bcnt, const int* __restrict__ bbase,
    int* __restrict__ deg, int* __restrict__ rowptr, float* __restrict__ dinv,
    unsigned* __restrict__ epacked, int N){
  __shared__ unsigned ebuf[BCAP];
  __shared__ int cnt[64], lscan[64], lcur[64];
  int b = blockIdx.x, t = threadIdx.x;
  int b0 = b << BSH;
  int nE = min(bcnt[b], BCAP);
  int base = bbase[b];
  if (t<64) cnt[t]=0;
  __syncthreads();
  for (int i=t;i<nE;i+=256){
    unsigned v = bedges[(size_t)b*BCAP + i];
    ebuf[i]=v;
    atomicAdd(&cnt[(v>>16) & ((1u<<BSH)-1u)],1);
  }
  __syncthreads();
  if (t==0){ int run=0; for (int i=0;i<64;i++){ lscan[i]=run; run+=cnt[i]; } }
  __syncthreads();
  if (t<64){
    int node = b0 + t;
    if (node < N){
      deg[node] = cnt[t];
      dinv[node] = rsqrtf((float)cnt[t] + 1.0f);
      rowptr[node] = base + lscan[t];
    }
    lcur[t] = lscan[t];
  }
  __syncthreads();
  for (int i=t;i<nE;i+=256){
    unsigned v = ebuf[i];
    int dl = (int)((v>>16) & ((1u<<BSH)-1u));
    int pos = base + atomicAdd(&lcur[dl],1);
    epacked[pos] = v;
  }
}

// fused: weight pre-split [0,448) + acc init [448,448+NI) + csrc/cw unpack (rest)
__global__ __launch_bounds__(256) void k_prep_misc(const float* __restrict__ convW,
    const float* __restrict__ linW, const float* __restrict__ mlpW,
    unsigned short* __restrict__ wsplit,
    const float* __restrict__ emb, const int* __restrict__ xidx,
    unsigned short* __restrict__ accb, int n, int NI,
    const unsigned* __restrict__ epacked, const float* __restrict__ dinv,
    int* __restrict__ csrc, float* __restrict__ cw, int E){
  if (blockIdx.x < 448){
    int idx = blockIdx.x*256 + threadIdx.x;   // 7*16384 total
    int mat = idx >> 14, rem = idx & 16383;
    int k = rem >> 7, col = rem & 127;
    const float* Wp = (mat < 3) ? (convW + (size_t)mat*16384)
                    : (mat < 6) ? (linW + (size_t)(mat-3)*16384)
                                : mlpW;
    float w = Wp[k*HID + col];
    unsigned short hi = f2bf(w);
    unsigned short lo = f2bf(w - bf2f(hi));
    int ks = k>>5, kg = (k>>3)&3, j = k&7, ct = col>>4, c = col&15;
    size_t base = (((size_t)(mat*2)*4 + ks)*8 + ct)*1024 + (size_t)(kg*16 + c)*8 + j;
    wsplit[base] = hi;
    wsplit[base + 32768] = lo;   // hilo stride = 4*8*1024
  } else if (blockIdx.x < 448 + NI){
    int i = (blockIdx.x-448)*256 + threadIdx.x;
    int total = n*32;
    if (i<total){
      int nn = i>>5, q = i&31;
      float4 v = ((const float4*)emb)[xidx[nn]*32+q];
      ushort4 w;
      w.x=f2bf(v.x); w.y=f2bf(v.y); w.z=f2bf(v.z); w.w=f2bf(v.w);
      ((ushort4*)accb)[i]=w;
    }
  } else {
    int i = (blockIdx.x-448-NI)*256 + threadIdx.x;
    if (i < E){
      unsigned v = epacked[i];
      int s = (int)(v & 0xFFFFu);
      int d = (int)(v >> 16);
      csrc[i] = s;
      cw[i] = dinv[s]*dinv[d];
    }
  }
}

// MFMA GEMM, bf16 A (exact): acc += A@Wh + A@Wl  == A @ (fp32ish W).
// BM=64, 256 thr (4 waves), wave wv owns coltiles {wv, wv+4}.
template<bool DUAL>
__global__ __launch_bounds__(256) void k_mm(
    const unsigned short* __restrict__ A, const unsigned short* __restrict__ wsplit,
    int mat0, int mat1,
    const float* __restrict__ b0, const float* __restrict__ b1,
    const float* __restrict__ dinv,
    unsigned short* __restrict__ O0b, unsigned short* __restrict__ O1b, int n)
{
  __shared__ unsigned short ash[4][2048];  // [ks][mt(4)][kg(4)][r(16)][j(8)]
  int tid = threadIdx.x;
  int lane = tid & 63;
  int wv = tid >> 6;            // 0..3
  int n0 = blockIdx.x * 64;

  f32x4 acc0[4][2]; f32x4 acc1[DUAL?4:1][DUAL?2:1];
  #pragma unroll
  for (int mt=0; mt<4; ++mt){
    #pragma unroll
    for (int c=0;c<2;c++){ acc0[mt][c]=(f32x4)0.f; if (DUAL) acc1[mt][c]=(f32x4)0.f; }
  }

  int srow = tid >> 2;          // 0..63
  int skg  = tid & 3;
  bool svalid = (n0 + srow) < n;
  const unsigned short* aptr = A + (size_t)(n0 + srow)*HID + skg*8;
  int selem = (srow>>4)*512 + skg*128 + (srow&15)*8;

  #pragma unroll
  for (int ks=0; ks<4; ++ks){
    bf16x8 v = {0,0,0,0,0,0,0,0};
    if (svalid) v = *(const bf16x8*)(aptr + ks*32);
    *(bf16x8*)&ash[ks][selem] = v;
  }
  __syncthreads();

  int flane = ((lane>>4)*128) + ((lane&15)*8);
  int ct0 = wv, ct1 = wv + 4;

  for (int ks=0; ks<4; ++ks){
    bf16x8 ah[4];
    #pragma unroll
    for (int mt=0; mt<4; ++mt) ah[mt] = *(const bf16x8*)&ash[ks][mt*512 + flane];
    {
      size_t wb = (((size_t)(mat0*2)*4 + ks)*8)*1024 + flane;
      bf16x8 wh0 = *(const bf16x8*)&wsplit[wb + (size_t)ct0*1024];
      bf16x8 wl0 = *(const bf16x8*)&wsplit[wb + (size_t)ct0*1024 + 32768];
      bf16x8 wh1 = *(const bf16x8*)&wsplit[wb + (size_t)ct1*1024];
      bf16x8 wl1 = *(const bf16x8*)&wsplit[wb + (size_t)ct1*1024 + 32768];
      #pragma unroll
      for (int mt=0; mt<4; ++mt){
        acc0[mt][0] = __builtin_amdgcn_mfma_f32_16x16x32_bf16(ah[mt], wh0, acc0[mt][0], 0,0,0);
        acc0[mt][0] = __builtin_amdgcn_mfma_f32_16x16x32_bf16(ah[mt], wl0, acc0[mt][0], 0,0,0);
        acc0[mt][1] = __builtin_amdgcn_mfma_f32_16x16x32_bf16(ah[mt], wh1, acc0[mt][1], 0,0,0);
        acc0[mt][1] = __builtin_amdgcn_mfma_f32_16x16x32_bf16(ah[mt], wl1, acc0[mt][1], 0,0,0);
      }
    }
    if (DUAL){
      size_t wb = (((size_t)(mat1*2)*4 + ks)*8)*1024 + flane;
      bf16x8 wh0 = *(const bf16x8*)&wsplit[wb + (size_t)ct0*1024];
      bf16x8 wl0 = *(const bf16x8*)&wsplit[wb + (size_t)ct0*1024 + 32768];
      bf16x8 wh1 = *(const bf16x8*)&wsplit[wb + (size_t)ct1*1024];
      bf16x8 wl1 = *(const bf16x8*)&wsplit[wb + (size_t)ct1*1024 + 32768];
      #pragma unroll
      for (int mt=0; mt<4; ++mt){
        acc1[mt][0] = __builtin_amdgcn_mfma_f32_16x16x32_bf16(ah[mt], wh0, acc1[mt][0], 0,0,0);
        acc1[mt][0] = __builtin_amdgcn_mfma_f32_16x16x32_bf16(ah[mt], wl0, acc1[mt][0], 0,0,0);
        acc1[mt][1] = __builtin_amdgcn_mfma_f32_16x16x32_bf16(ah[mt], wh1, acc1[mt][1], 0,0,0);
        acc1[mt][1] = __builtin_amdgcn_mfma_f32_16x16x32_bf16(ah[mt], wl1, acc1[mt][1], 0,0,0);
      }
    }
  }

  // epilogue: D[i][c]: i=(lane>>4)*4+r, c=lane&15
  int cA = ct0*16 + (lane&15);
  int cB = ct1*16 + (lane&15);
  float bb0A = b0[cA], bb0B = b0[cB];
  float bb1A = DUAL ? b1[cA] : 0.f;
  float bb1B = DUAL ? b1[cB] : 0.f;
  #pragma unroll
  for (int mt=0; mt<4; ++mt){
    #pragma unroll
    for (int r=0; r<4; ++r){
      int gn = n0 + mt*16 + (lane>>4)*4 + r;
      if (gn >= n) continue;
      float xA = acc0[mt][0][r];
      float xB = acc0[mt][1][r];
      if (DUAL){
        float dn = dinv[gn]; float snm = dn*dn;
        O0b[(size_t)gn*HID + cA] = f2bf(xA);
        O0b[(size_t)gn*HID + cB] = f2bf(xB);
        O1b[(size_t)gn*HID + cA] = f2bf(acc1[mt][0][r] + bb0A + bb1A + xA*snm);
        O1b[(size_t)gn*HID + cB] = f2bf(acc1[mt][1][r] + bb0B + bb1B + xB*snm);
      } else {
        O0b[(size_t)gn*HID + cA] = f2bf(eluf(xA + bb0A));
        O0b[(size_t)gn*HID + cB] = f2bf(eluf(xB + bb0B));
      }
    }
  }
}

// one wave per node: wave-uniform edge indices (scalar csrc/cw loads),
// ALWAYS 8 gathers in flight — tail handled by clamped index + zero weight.
__global__ __launch_bounds__(256) void k_agg(const unsigned* __restrict__ xwb,
    const unsigned* __restrict__ baseb, unsigned* __restrict__ accb,
    const int* __restrict__ rowptr, const int* __restrict__ deg,
    const int* __restrict__ csrc, const float* __restrict__ cw, int n)
{
  int wid = threadIdx.x>>6, lane = threadIdx.x & 63;
  int node = __builtin_amdgcn_readfirstlane(blockIdx.x*4 + wid);
  if (node>=n) return;
  int s = rowptr[node], e = s + deg[node];
  float s0=0.f, s1=0.f;
  for (int p = s; p < e; p += 8){
    #pragma unroll
    for (int j=0;j<8;j++){
      int idx = p + j;
      int idc = min(idx, e-1);
      int u = csrc[idc];
      float w = (idx < e) ? cw[idc] : 0.f;
      unsigned a = xwb[u*64 + lane];
      s0 += w*bflo(a); s1 += w*bfhi(a);
    }
  }
  unsigned bb = baseb[(size_t)node*64 + lane];
  float x0 = eluf(bflo(bb) + s0), x1 = eluf(bfhi(bb) + s1);
  unsigned av = accb[(size_t)node*64 + lane];
  accb[(size_t)node*64 + lane] = packbf(bflo(av) + x0, bfhi(av) + x1);
}

static __device__ __forceinline__ int lowerb(const int* a, int nn, int key){
  int lo=0, hi=nn;
  while (lo<hi){ int m=(lo+hi)>>1; if (a[m]<key) lo=m+1; else hi=m; }
  return lo;
}

// deterministic 2-stage pooling, stage 1 (bf16 input)
__global__ __launch_bounds__(128) void k_pool_part(const unsigned short* __restrict__ x,
                                                   const int* __restrict__ batch,
                                                   float* __restrict__ part, int n){
  int g = blockIdx.x / POOL_S, s = blockIdx.x % POOL_S;
  int d = threadIdx.x;
  int lo = lowerb(batch, n, g), hi = lowerb(batch, n, g+1);
  float sum = 0.f;
  for (int r = lo + s; r < hi; r += POOL_S) sum += bf2f(x[(size_t)r*HID + d]);
  part[blockIdx.x*HID + d] = sum;
}

__global__ __launch_bounds__(128) void k_pred(const float* __restrict__ part, const float* __restrict__ W,
                                              const float* __restrict__ b, float* __restrict__ out, int G){
  __shared__ float pr[HID];
  int g = blockIdx.x, o = threadIdx.x;
  float s = 0.f;
  #pragma unroll
  for (int q=0;q<POOL_S;q++) s += part[(g*POOL_S+q)*HID + o];
  pr[o] = s;
  __syncthreads();
  float acc = b[o];
  #pragma unroll 8
  for (int k=0;k<HID;k++) acc += pr[k]*W[k*HID+o];
  out[g*HID+o] = acc*0.1f;
}

extern "C" void kernel_launch(void* const* d_in, const int* in_sizes, int n_in,
                              void* d_out, int out_size, void* d_ws, size_t ws_size,
                              hipStream_t stream)
{
  const int*   x_idx  = (const int*)d_in[0];
  const int*   eidx   = (const int*)d_in[1];
  const int*   batch  = (const int*)d_in[2];
  const float* emb    = (const float*)d_in[3];
  const float* convW  = (const float*)d_in[4];
  const float* convb  = (const float*)d_in[5];
  const float* linW   = (const float*)d_in[6];
  const float* linb   = (const float*)d_in[7];
  const float* mlpW   = (const float*)d_in[8];
  const float* mlpb   = (const float*)d_in[9];
  const float* predW  = (const float*)d_in[10];
  const float* predb  = (const float*)d_in[11];
  float* out = (float*)d_out;
  int N = in_sizes[0];
  int E = in_sizes[1]/2;
  int G = out_size / 128;   // OUT = 128
  int NB = (N + (1<<BSH) - 1) >> BSH;

  char* p = (char*)d_ws;
  auto alloc = [&](size_t bytes)->char*{ char* q = p; p += (bytes + 255) & ~(size_t)255; return q; };
  int*   deg    = (int*)  alloc((size_t)N*4);
  int*   rowptr = (int*)  alloc((size_t)N*4);
  int*   bcnt   = (int*)  alloc((size_t)NB*4);
  int*   bbase  = (int*)  alloc((size_t)NB*4);
  float* dinv   = (float*)alloc((size_t)N*4);
  int*   csrc   = (int*)  alloc((size_t)E*4);
  float* cw     = (float*)alloc((size_t)E*4);
  unsigned* epacked = (unsigned*)alloc((size_t)E*4);
  unsigned short* accb  = (unsigned short*)alloc((size_t)N*HID*2);
  unsigned short* xwb   = (unsigned short*)alloc((size_t)N*HID*2);
  unsigned short* baseb = (unsigned short*)alloc((size_t)N*HID*2);
  float* part   = (float*)alloc((size_t)G*POOL_S*HID*4);
  unsigned* bedges = (unsigned*)alloc((size_t)NB*BCAP*4);
  unsigned short* wsplit = (unsigned short*)alloc((size_t)7*2*16384*2);
  if ((size_t)(p - (char*)d_ws) > ws_size) return; // ws too small: leave poison -> loud failure

  const int* src = eidx;
  const int* dst = eidx + E;

  hipMemsetAsync(bcnt, 0, (size_t)NB*4, stream);
  k_bucket<<<(E+2047)/2048,256,0,stream>>>(src, dst, bcnt, bedges, E, NB);
  k_scan_bcnt<<<1,1024,0,stream>>>(bcnt, bbase, NB);
  k_csr<<<NB,256,0,stream>>>(bedges, bcnt, bbase, deg, rowptr, dinv, epacked, N);
  int NI = (N*32+255)/256;
  int NC = (E+255)/256;
  k_prep_misc<<<448+NI+NC,256,0,stream>>>(convW, linW, mlpW, wsplit,
                                          emb, x_idx, accb, N, NI,
                                          epacked, dinv, csrc, cw, E);

  int mblk = (N+63)/64;
  for (int l=0;l<3;l++){
    k_mm<true><<<mblk,256,0,stream>>>(accb, wsplit, l, 3+l,
                                      convb + l*HID, linb + l*HID, dinv,
                                      xwb, baseb, N);
    k_agg<<<(N+3)/4,256,0,stream>>>((const unsigned*)xwb, (const unsigned*)baseb,
                                    (unsigned*)accb, rowptr, deg, csrc, cw, N);
  }
  k_mm<false><<<mblk,256,0,stream>>>(accb, wsplit, 6, 6, mlpb, nullptr, nullptr,
                                     xwb, nullptr, N);
  k_pool_part<<<G*POOL_S,128,0,stream>>>(xwb, batch, part, N);
  k_pred<<<G,128,0,stream>>>(part, predW, predb, out, G);
}

// Round 13
// 244.575 us; speedup vs baseline: 1.0605x; 1.0605x over previous
//
#include <hip/hip_runtime.h>
#include <math.h>

#define HID 128
#define POOL_S 8
#define BSH 6        // nodes per bucket = 64
#define BCAP 2048    // bucket capacity (mean ~1024 at E=800K, NB=782)

typedef __attribute__((ext_vector_type(8))) short bf16x8;
typedef __attribute__((ext_vector_type(4))) float f32x4;

static __device__ __forceinline__ float eluf(float x){ return x > 0.f ? x : expm1f(x); }

// round-to-nearest-even f32 -> bf16 bits
static __device__ __forceinline__ unsigned short f2bf(float f){
  unsigned u = __builtin_bit_cast(unsigned, f);
  u += 0x7fffu + ((u >> 16) & 1u);
  return (unsigned short)(u >> 16);
}
static __device__ __forceinline__ float bf2f(unsigned short h){
  return __builtin_bit_cast(float, (unsigned)h << 16);
}
static __device__ __forceinline__ float bflo(unsigned u){ return __builtin_bit_cast(float, u << 16); }
static __device__ __forceinline__ float bfhi(unsigned u){ return __builtin_bit_cast(float, u & 0xffff0000u); }
static __device__ __forceinline__ unsigned packbf(float a, float b){
  return (unsigned)f2bf(a) | ((unsigned)f2bf(b) << 16);
}

// fused pass 1: blocks [0,NBU): bucket edges by dst>>BSH (entry=(d<<16)|s);
// [NBU,NBU+448): weight pre-split; rest: acc init. (wsplit/init independent of graph)
__global__ __launch_bounds__(256) void k_bucket_prep(const int* __restrict__ src, const int* __restrict__ dst,
    int* __restrict__ bcnt, unsigned* __restrict__ bedges, int E, int NB, int NBU,
    const float* __restrict__ convW, const float* __restrict__ linW, const float* __restrict__ mlpW,
    unsigned short* __restrict__ wsplit,
    const float* __restrict__ emb, const int* __restrict__ xidx,
    unsigned short* __restrict__ accb, int n){
  if (blockIdx.x < (unsigned)NBU){
    __shared__ int hist[1024];
    __shared__ int base[1024];
    int t = threadIdx.x;
    int e0 = blockIdx.x * 2048;
    int e1 = min(e0 + 2048, E);
    for (int i=t;i<NB;i+=256) hist[i]=0;
    __syncthreads();
    for (int e=e0+t; e<e1; e+=256) atomicAdd(&hist[dst[e]>>BSH],1);
    __syncthreads();
    for (int i=t;i<NB;i+=256){
      int c = hist[i];
      base[i] = (c>0) ? atomicAdd(&bcnt[i], c) : 0;
      hist[i] = 0;   // reuse as local cursor
    }
    __syncthreads();
    for (int e=e0+t; e<e1; e+=256){
      int d = dst[e], s = src[e];
      int b = d>>BSH;
      int off = base[b] + atomicAdd(&hist[b],1);
      if (off < BCAP)
        bedges[(size_t)b*BCAP + off] = ((unsigned)d << 16) | (unsigned)s;
    }
  } else if (blockIdx.x < (unsigned)(NBU + 448)){
    int idx = (blockIdx.x-NBU)*256 + threadIdx.x;   // 7*16384 total
    int mat = idx >> 14, rem = idx & 16383;
    int k = rem >> 7, col = rem & 127;
    const float* Wp = (mat < 3) ? (convW + (size_t)mat*16384)
                    : (mat < 6) ? (linW + (size_t)(mat-3)*16384)
                                : mlpW;
    float w = Wp[k*HID + col];
    unsigned short hi = f2bf(w);
    unsigned short lo = f2bf(w - bf2f(hi));
    int ks = k>>5, kg = (k>>3)&3, j = k&7, ct = col>>4, c = col&15;
    size_t base = (((size_t)(mat*2)*4 + ks)*8 + ct)*1024 + (size_t)(kg*16 + c)*8 + j;
    wsplit[base] = hi;
    wsplit[base + 32768] = lo;   // hilo stride = 4*8*1024
  } else {
    int i = (blockIdx.x-NBU-448)*256 + threadIdx.x;
    int total = n*32;
    if (i<total){
      int nn = i>>5, q = i&31;
      float4 v = ((const float4*)emb)[xidx[nn]*32+q];
      ushort4 w;
      w.x=f2bf(v.x); w.y=f2bf(v.y); w.z=f2bf(v.z); w.w=f2bf(v.w);
      ((ushort4*)accb)[i]=w;
    }
  }
}

// exclusive scan of bcnt (NB <= 1024) in one block
__global__ __launch_bounds__(1024) void k_scan_bcnt(const int* __restrict__ bcnt,
                                                    int* __restrict__ bbase, int NB){
  __shared__ int ts[1024];
  int t = threadIdx.x;
  int v = (t<NB) ? bcnt[t] : 0;
  ts[t]=v; __syncthreads();
  for (int off=1; off<1024; off<<=1){
    int x = (t>=off)?ts[t-off]:0; __syncthreads();
    ts[t]+=x; __syncthreads();
  }
  if (t<NB) bbase[t] = ts[t]-v;
}

// pass 2: per bucket: LDS count -> deg/dinv/rowptr, then scatter packed entries
__global__ __launch_bounds__(256) void k_csr(const unsigned* __restrict__ bedges,
    const int* __restrict__ bcnt, const int* __restrict__ bbase,
    int* __restrict__ deg, int* __restrict__ rowptr, float* __restrict__ dinv,
    unsigned* __restrict__ epacked, int N){
  __shared__ unsigned ebuf[BCAP];
  __shared__ int cnt[64], lscan[64], lcur[64];
  int b = blockIdx.x, t = threadIdx.x;
  int b0 = b << BSH;
  int nE = min(bcnt[b], BCAP);
  int base = bbase[b];
  if (t<64) cnt[t]=0;
  __syncthreads();
  for (int i=t;i<nE;i+=256){
    unsigned v = bedges[(size_t)b*BCAP + i];
    ebuf[i]=v;
    atomicAdd(&cnt[(v>>16) & ((1u<<BSH)-1u)],1);
  }
  __syncthreads();
  if (t==0){ int run=0; for (int i=0;i<64;i++){ lscan[i]=run; run+=cnt[i]; } }
  __syncthreads();
  if (t<64){
    int node = b0 + t;
    if (node < N){
      deg[node] = cnt[t];
      dinv[node] = rsqrtf((float)cnt[t] + 1.0f);
      rowptr[node] = base + lscan[t];
    }
    lcur[t] = lscan[t];
  }
  __syncthreads();
  for (int i=t;i<nE;i+=256){
    unsigned v = ebuf[i];
    int dl = (int)((v>>16) & ((1u<<BSH)-1u));
    int pos = base + atomicAdd(&lcur[dl],1);
    epacked[pos] = v;
  }
}

// pass 3 (streaming, coalesced): unpack csrc + compute cw
__global__ __launch_bounds__(256) void k_cw(const unsigned* __restrict__ epacked,
    const float* __restrict__ dinv, int* __restrict__ csrc, float* __restrict__ cw, int E){
  int i = blockIdx.x*256 + threadIdx.x;
  if (i < E){
    unsigned v = epacked[i];
    int s = (int)(v & 0xFFFFu);
    int d = (int)(v >> 16);
    csrc[i] = s;
    cw[i] = dinv[s]*dinv[d];
  }
}

// MFMA GEMM, bf16 A (exact): acc += A@Wh + A@Wl  == A @ (fp32ish W).
// BM=64, 256 thr (4 waves), wave wv owns coltiles {wv, wv+4}.
template<bool DUAL>
__global__ __launch_bounds__(256) void k_mm(
    const unsigned short* __restrict__ A, const unsigned short* __restrict__ wsplit,
    int mat0, int mat1,
    const float* __restrict__ b0, const float* __restrict__ b1,
    const float* __restrict__ dinv,
    unsigned short* __restrict__ O0b, unsigned short* __restrict__ O1b, int n)
{
  __shared__ unsigned short ash[4][2048];  // [ks][mt(4)][kg(4)][r(16)][j(8)]
  int tid = threadIdx.x;
  int lane = tid & 63;
  int wv = tid >> 6;            // 0..3
  int n0 = blockIdx.x * 64;

  f32x4 acc0[4][2]; f32x4 acc1[DUAL?4:1][DUAL?2:1];
  #pragma unroll
  for (int mt=0; mt<4; ++mt){
    #pragma unroll
    for (int c=0;c<2;c++){ acc0[mt][c]=(f32x4)0.f; if (DUAL) acc1[mt][c]=(f32x4)0.f; }
  }

  int srow = tid >> 2;          // 0..63
  int skg  = tid & 3;
  bool svalid = (n0 + srow) < n;
  const unsigned short* aptr = A + (size_t)(n0 + srow)*HID + skg*8;
  int selem = (srow>>4)*512 + skg*128 + (srow&15)*8;

  #pragma unroll
  for (int ks=0; ks<4; ++ks){
    bf16x8 v = {0,0,0,0,0,0,0,0};
    if (svalid) v = *(const bf16x8*)(aptr + ks*32);
    *(bf16x8*)&ash[ks][selem] = v;
  }
  __syncthreads();

  int flane = ((lane>>4)*128) + ((lane&15)*8);
  int ct0 = wv, ct1 = wv + 4;

  for (int ks=0; ks<4; ++ks){
    bf16x8 ah[4];
    #pragma unroll
    for (int mt=0; mt<4; ++mt) ah[mt] = *(const bf16x8*)&ash[ks][mt*512 + flane];
    {
      size_t wb = (((size_t)(mat0*2)*4 + ks)*8)*1024 + flane;
      bf16x8 wh0 = *(const bf16x8*)&wsplit[wb + (size_t)ct0*1024];
      bf16x8 wl0 = *(const bf16x8*)&wsplit[wb + (size_t)ct0*1024 + 32768];
      bf16x8 wh1 = *(const bf16x8*)&wsplit[wb + (size_t)ct1*1024];
      bf16x8 wl1 = *(const bf16x8*)&wsplit[wb + (size_t)ct1*1024 + 32768];
      #pragma unroll
      for (int mt=0; mt<4; ++mt){
        acc0[mt][0] = __builtin_amdgcn_mfma_f32_16x16x32_bf16(ah[mt], wh0, acc0[mt][0], 0,0,0);
        acc0[mt][0] = __builtin_amdgcn_mfma_f32_16x16x32_bf16(ah[mt], wl0, acc0[mt][0], 0,0,0);
        acc0[mt][1] = __builtin_amdgcn_mfma_f32_16x16x32_bf16(ah[mt], wh1, acc0[mt][1], 0,0,0);
        acc0[mt][1] = __builtin_amdgcn_mfma_f32_16x16x32_bf16(ah[mt], wl1, acc0[mt][1], 0,0,0);
      }
    }
    if (DUAL){
      size_t wb = (((size_t)(mat1*2)*4 + ks)*8)*1024 + flane;
      bf16x8 wh0 = *(const bf16x8*)&wsplit[wb + (size_t)ct0*1024];
      bf16x8 wl0 = *(const bf16x8*)&wsplit[wb + (size_t)ct0*1024 + 32768];
      bf16x8 wh1 = *(const bf16x8*)&wsplit[wb + (size_t)ct1*1024];
      bf16x8 wl1 = *(const bf16x8*)&wsplit[wb + (size_t)ct1*1024 + 32768];
      #pragma unroll
      for (int mt=0; mt<4; ++mt){
        acc1[mt][0] = __builtin_amdgcn_mfma_f32_16x16x32_bf16(ah[mt], wh0, acc1[mt][0], 0,0,0);
        acc1[mt][0] = __builtin_amdgcn_mfma_f32_16x16x32_bf16(ah[mt], wl0, acc1[mt][0], 0,0,0);
        acc1[mt][1] = __builtin_amdgcn_mfma_f32_16x16x32_bf16(ah[mt], wh1, acc1[mt][1], 0,0,0);
        acc1[mt][1] = __builtin_amdgcn_mfma_f32_16x16x32_bf16(ah[mt], wl1, acc1[mt][1], 0,0,0);
      }
    }
  }

  // epilogue: D[i][c]: i=(lane>>4)*4+r, c=lane&15
  int cA = ct0*16 + (lane&15);
  int cB = ct1*16 + (lane&15);
  float bb0A = b0[cA], bb0B = b0[cB];
  float bb1A = DUAL ? b1[cA] : 0.f;
  float bb1B = DUAL ? b1[cB] : 0.f;
  #pragma unroll
  for (int mt=0; mt<4; ++mt){
    #pragma unroll
    for (int r=0; r<4; ++r){
      int gn = n0 + mt*16 + (lane>>4)*4 + r;
      if (gn >= n) continue;
      float xA = acc0[mt][0][r];
      float xB = acc0[mt][1][r];
      if (DUAL){
        float dn = dinv[gn]; float snm = dn*dn;
        O0b[(size_t)gn*HID + cA] = f2bf(xA);
        O0b[(size_t)gn*HID + cB] = f2bf(xB);
        O1b[(size_t)gn*HID + cA] = f2bf(acc1[mt][0][r] + bb0A + bb1A + xA*snm);
        O1b[(size_t)gn*HID + cB] = f2bf(acc1[mt][1][r] + bb0B + bb1B + xB*snm);
      } else {
        O0b[(size_t)gn*HID + cA] = f2bf(eluf(xA + bb0A));
        O0b[(size_t)gn*HID + cB] = f2bf(eluf(xB + bb0B));
      }
    }
  }
}

// one wave per node: wave-uniform AFFINE edge indices -> wide scalar csrc/cw loads,
// 8 independent bf16 row gathers in flight; serial tail; fuse elu + bf16-acc update.
__global__ __launch_bounds__(256) void k_agg(const unsigned* __restrict__ xwb,
    const unsigned* __restrict__ baseb, unsigned* __restrict__ accb,
    const int* __restrict__ rowptr, const int* __restrict__ deg,
    const int* __restrict__ csrc, const float* __restrict__ cw, int n)
{
  int wid = threadIdx.x>>6, lane = threadIdx.x & 63;
  int node = __builtin_amdgcn_readfirstlane(blockIdx.x*4 + wid);
  if (node>=n) return;
  int s = rowptr[node], e = s + deg[node];
  float s0=0.f, s1=0.f;
  int p = s;
  for (; p+8<=e; p+=8){
    int u0=csrc[p],   u1=csrc[p+1], u2=csrc[p+2], u3=csrc[p+3];
    int u4=csrc[p+4], u5=csrc[p+5], u6=csrc[p+6], u7=csrc[p+7];
    unsigned a0 = xwb[u0*64 + lane];
    unsigned a1 = xwb[u1*64 + lane];
    unsigned a2 = xwb[u2*64 + lane];
    unsigned a3 = xwb[u3*64 + lane];
    unsigned a4 = xwb[u4*64 + lane];
    unsigned a5 = xwb[u5*64 + lane];
    unsigned a6 = xwb[u6*64 + lane];
    unsigned a7 = xwb[u7*64 + lane];
    float w0=cw[p],   w1=cw[p+1], w2=cw[p+2], w3=cw[p+3];
    float w4=cw[p+4], w5=cw[p+5], w6=cw[p+6], w7=cw[p+7];
    s0 += w0*bflo(a0); s1 += w0*bfhi(a0);
    s0 += w1*bflo(a1); s1 += w1*bfhi(a1);
    s0 += w2*bflo(a2); s1 += w2*bfhi(a2);
    s0 += w3*bflo(a3); s1 += w3*bfhi(a3);
    s0 += w4*bflo(a4); s1 += w4*bfhi(a4);
    s0 += w5*bflo(a5); s1 += w5*bfhi(a5);
    s0 += w6*bflo(a6); s1 += w6*bfhi(a6);
    s0 += w7*bflo(a7); s1 += w7*bfhi(a7);
  }
  for (; p<e; p++){
    int u = csrc[p]; float w = cw[p];
    unsigned a = xwb[u*64 + lane];
    s0 += w*bflo(a); s1 += w*bfhi(a);
  }
  unsigned bb = baseb[(size_t)node*64 + lane];
  float x0 = eluf(bflo(bb) + s0), x1 = eluf(bfhi(bb) + s1);
  unsigned av = accb[(size_t)node*64 + lane];
  accb[(size_t)node*64 + lane] = packbf(bflo(av) + x0, bfhi(av) + x1);
}

static __device__ __forceinline__ int lowerb(const int* a, int nn, int key){
  int lo=0, hi=nn;
  while (lo<hi){ int m=(lo+hi)>>1; if (a[m]<key) lo=m+1; else hi=m; }
  return lo;
}

// deterministic 2-stage pooling, stage 1 (bf16 input)
__global__ __launch_bounds__(128) void k_pool_part(const unsigned short* __restrict__ x,
                                                   const int* __restrict__ batch,
                                                   float* __restrict__ part, int n){
  int g = blockIdx.x / POOL_S, s = blockIdx.x % POOL_S;
  int d = threadIdx.x;
  int lo = lowerb(batch, n, g), hi = lowerb(batch, n, g+1);
  float sum = 0.f;
  for (int r = lo + s; r < hi; r += POOL_S) sum += bf2f(x[(size_t)r*HID + d]);
  part[blockIdx.x*HID + d] = sum;
}

__global__ __launch_bounds__(128) void k_pred(const float* __restrict__ part, const float* __restrict__ W,
                                              const float* __restrict__ b, float* __restrict__ out, int G){
  __shared__ float pr[HID];
  int g = blockIdx.x, o = threadIdx.x;
  float s = 0.f;
  #pragma unroll
  for (int q=0;q<POOL_S;q++) s += part[(g*POOL_S+q)*HID + o];
  pr[o] = s;
  __syncthreads();
  float acc = b[o];
  #pragma unroll 8
  for (int k=0;k<HID;k++) acc += pr[k]*W[k*HID+o];
  out[g*HID+o] = acc*0.1f;
}

extern "C" void kernel_launch(void* const* d_in, const int* in_sizes, int n_in,
                              void* d_out, int out_size, void* d_ws, size_t ws_size,
                              hipStream_t stream)
{
  const int*   x_idx  = (const int*)d_in[0];
  const int*   eidx   = (const int*)d_in[1];
  const int*   batch  = (const int*)d_in[2];
  const float* emb    = (const float*)d_in[3];
  const float* convW  = (const float*)d_in[4];
  const float* convb  = (const float*)d_in[5];
  const float* linW   = (const float*)d_in[6];
  const float* linb   = (const float*)d_in[7];
  const float* mlpW   = (const float*)d_in[8];
  const float* mlpb   = (const float*)d_in[9];
  const float* predW  = (const float*)d_in[10];
  const float* predb  = (const float*)d_in[11];
  float* out = (float*)d_out;
  int N = in_sizes[0];
  int E = in_sizes[1]/2;
  int G = out_size / 128;   // OUT = 128
  int NB = (N + (1<<BSH) - 1) >> BSH;

  char* p = (char*)d_ws;
  auto alloc = [&](size_t bytes)->char*{ char* q = p; p += (bytes + 255) & ~(size_t)255; return q; };
  int*   deg    = (int*)  alloc((size_t)N*4);
  int*   rowptr = (int*)  alloc((size_t)N*4);
  int*   bcnt   = (int*)  alloc((size_t)NB*4);
  int*   bbase  = (int*)  alloc((size_t)NB*4);
  float* dinv   = (float*)alloc((size_t)N*4);
  int*   csrc   = (int*)  alloc((size_t)E*4);
  float* cw     = (float*)alloc((size_t)E*4);
  unsigned* epacked = (unsigned*)alloc((size_t)E*4);
  unsigned short* accb  = (unsigned short*)alloc((size_t)N*HID*2);
  unsigned short* xwb   = (unsigned short*)alloc((size_t)N*HID*2);
  unsigned short* baseb = (unsigned short*)alloc((size_t)N*HID*2);
  float* part   = (float*)alloc((size_t)G*POOL_S*HID*4);
  unsigned* bedges = (unsigned*)alloc((size_t)NB*BCAP*4);
  unsigned short* wsplit = (unsigned short*)alloc((size_t)7*2*16384*2);
  if ((size_t)(p - (char*)d_ws) > ws_size) return; // ws too small: leave poison -> loud failure

  const int* src = eidx;
  const int* dst = eidx + E;

  hipMemsetAsync(bcnt, 0, (size_t)NB*4, stream);
  int NBU = (E+2047)/2048;
  int NI  = (N*32+255)/256;
  k_bucket_prep<<<NBU+448+NI,256,0,stream>>>(src, dst, bcnt, bedges, E, NB, NBU,
                                             convW, linW, mlpW, wsplit,
                                             emb, x_idx, accb, N);
  k_scan_bcnt<<<1,1024,0,stream>>>(bcnt, bbase, NB);
  k_csr<<<NB,256,0,stream>>>(bedges, bcnt, bbase, deg, rowptr, dinv, epacked, N);
  k_cw<<<(E+255)/256,256,0,stream>>>(epacked, dinv, csrc, cw, E);

  int mblk = (N+63)/64;
  for (int l=0;l<3;l++){
    k_mm<true><<<mblk,256,0,stream>>>(accb, wsplit, l, 3+l,
                                      convb + l*HID, linb + l*HID, dinv,
                                      xwb, baseb, N);
    k_agg<<<(N+3)/4,256,0,stream>>>((const unsigned*)xwb, (const unsigned*)baseb,
                                    (unsigned*)accb, rowptr, deg, csrc, cw, N);
  }
  k_mm<false><<<mblk,256,0,stream>>>(accb, wsplit, 6, 6, mlpb, nullptr, nullptr,
                                     xwb, nullptr, N);
  k_pool_part<<<G*POOL_S,128,0,stream>>>(xwb, batch, part, N);
  k_pred<<<G,128,0,stream>>>(part, predW, predb, out, G);
}

// Round 14
// 242.130 us; speedup vs baseline: 1.0712x; 1.0101x over previous
//
#include <hip/hip_runtime.h>
#include <math.h>

#define HID 128
#define POOL_S 8
#define BSH 6        // nodes per bucket = 64
#define BCAP 2048    // bucket capacity (mean ~1024 at E=800K, NB=782)

typedef __attribute__((ext_vector_type(8))) short bf16x8;
typedef __attribute__((ext_vector_type(4))) float f32x4;

static __device__ __forceinline__ float eluf(float x){ return x > 0.f ? x : expm1f(x); }

// round-to-nearest-even f32 -> bf16 bits
static __device__ __forceinline__ unsigned short f2bf(float f){
  unsigned u = __builtin_bit_cast(unsigned, f);
  u += 0x7fffu + ((u >> 16) & 1u);
  return (unsigned short)(u >> 16);
}
static __device__ __forceinline__ float bf2f(unsigned short h){
  return __builtin_bit_cast(float, (unsigned)h << 16);
}
static __device__ __forceinline__ float bflo(unsigned u){ return __builtin_bit_cast(float, u << 16); }
static __device__ __forceinline__ float bfhi(unsigned u){ return __builtin_bit_cast(float, u & 0xffff0000u); }
static __device__ __forceinline__ unsigned packbf(float a, float b){
  return (unsigned)f2bf(a) | ((unsigned)f2bf(b) << 16);
}

// fused pass 1: blocks [0,NBU): bucket edges by dst>>BSH (entry=(d<<16)|s);
// [NBU,NBU+448): weight pre-split; rest: acc init.
__global__ __launch_bounds__(256) void k_bucket_prep(const int* __restrict__ src, const int* __restrict__ dst,
    int* __restrict__ bcnt, unsigned* __restrict__ bedges, int E, int NB, int NBU,
    const float* __restrict__ convW, const float* __restrict__ linW, const float* __restrict__ mlpW,
    unsigned short* __restrict__ wsplit,
    const float* __restrict__ emb, const int* __restrict__ xidx,
    unsigned short* __restrict__ accb, int n){
  if (blockIdx.x < (unsigned)NBU){
    __shared__ int hist[1024];
    __shared__ int base[1024];
    int t = threadIdx.x;
    int e0 = blockIdx.x * 2048;
    int e1 = min(e0 + 2048, E);
    for (int i=t;i<NB;i+=256) hist[i]=0;
    __syncthreads();
    for (int e=e0+t; e<e1; e+=256) atomicAdd(&hist[dst[e]>>BSH],1);
    __syncthreads();
    for (int i=t;i<NB;i+=256){
      int c = hist[i];
      base[i] = (c>0) ? atomicAdd(&bcnt[i], c) : 0;
      hist[i] = 0;   // reuse as local cursor
    }
    __syncthreads();
    for (int e=e0+t; e<e1; e+=256){
      int d = dst[e], s = src[e];
      int b = d>>BSH;
      int off = base[b] + atomicAdd(&hist[b],1);
      if (off < BCAP)
        bedges[(size_t)b*BCAP + off] = ((unsigned)d << 16) | (unsigned)s;
    }
  } else if (blockIdx.x < (unsigned)(NBU + 448)){
    int idx = (blockIdx.x-NBU)*256 + threadIdx.x;   // 7*16384 total
    int mat = idx >> 14, rem = idx & 16383;
    int k = rem >> 7, col = rem & 127;
    const float* Wp = (mat < 3) ? (convW + (size_t)mat*16384)
                    : (mat < 6) ? (linW + (size_t)(mat-3)*16384)
                                : mlpW;
    float w = Wp[k*HID + col];
    unsigned short hi = f2bf(w);
    unsigned short lo = f2bf(w - bf2f(hi));
    int ks = k>>5, kg = (k>>3)&3, j = k&7, ct = col>>4, c = col&15;
    size_t base = (((size_t)(mat*2)*4 + ks)*8 + ct)*1024 + (size_t)(kg*16 + c)*8 + j;
    wsplit[base] = hi;
    wsplit[base + 32768] = lo;   // hilo stride = 4*8*1024
  } else {
    int i = (blockIdx.x-NBU-448)*256 + threadIdx.x;
    int total = n*32;
    if (i<total){
      int nn = i>>5, q = i&31;
      float4 v = ((const float4*)emb)[xidx[nn]*32+q];
      ushort4 w;
      w.x=f2bf(v.x); w.y=f2bf(v.y); w.z=f2bf(v.z); w.w=f2bf(v.w);
      ((ushort4*)accb)[i]=w;
    }
  }
}

// exclusive scan of bcnt (NB <= 1024) in one block
__global__ __launch_bounds__(1024) void k_scan_bcnt(const int* __restrict__ bcnt,
                                                    int* __restrict__ bbase, int NB){
  __shared__ int ts[1024];
  int t = threadIdx.x;
  int v = (t<NB) ? bcnt[t] : 0;
  ts[t]=v; __syncthreads();
  for (int off=1; off<1024; off<<=1){
    int x = (t>=off)?ts[t-off]:0; __syncthreads();
    ts[t]+=x; __syncthreads();
  }
  if (t<NB) bbase[t] = ts[t]-v;
}

// pass 2: per bucket: LDS count -> deg/dinv/rowptr, then scatter packed entries
__global__ __launch_bounds__(256) void k_csr(const unsigned* __restrict__ bedges,
    const int* __restrict__ bcnt, const int* __restrict__ bbase,
    int* __restrict__ deg, int* __restrict__ rowptr, float* __restrict__ dinv,
    unsigned* __restrict__ epacked, int N){
  __shared__ unsigned ebuf[BCAP];
  __shared__ int cnt[64], lscan[64], lcur[64];
  int b = blockIdx.x, t = threadIdx.x;
  int b0 = b << BSH;
  int nE = min(bcnt[b], BCAP);
  int base = bbase[b];
  if (t<64) cnt[t]=0;
  __syncthreads();
  for (int i=t;i<nE;i+=256){
    unsigned v = bedges[(size_t)b*BCAP + i];
    ebuf[i]=v;
    atomicAdd(&cnt[(v>>16) & ((1u<<BSH)-1u)],1);
  }
  __syncthreads();
  if (t==0){ int run=0; for (int i=0;i<64;i++){ lscan[i]=run; run+=cnt[i]; } }
  __syncthreads();
  if (t<64){
    int node = b0 + t;
    if (node < N){
      deg[node] = cnt[t];
      dinv[node] = rsqrtf((float)cnt[t] + 1.0f);
      rowptr[node] = base + lscan[t];
    }
    lcur[t] = lscan[t];
  }
  __syncthreads();
  for (int i=t;i<nE;i+=256){
    unsigned v = ebuf[i];
    int dl = (int)((v>>16) & ((1u<<BSH)-1u));
    int pos = base + atomicAdd(&lcur[dl],1);
    epacked[pos] = v;
  }
}

// pass 3 (streaming, coalesced): unpack csrc + compute cw; writes 8 safe pad entries
__global__ __launch_bounds__(256) void k_cw(const unsigned* __restrict__ epacked,
    const float* __restrict__ dinv, int* __restrict__ csrc, float* __restrict__ cw, int E){
  int i = blockIdx.x*256 + threadIdx.x;
  if (i < E){
    unsigned v = epacked[i];
    int s = (int)(v & 0xFFFFu);
    int d = (int)(v >> 16);
    csrc[i] = s;
    cw[i] = dinv[s]*dinv[d];
  } else if (i < E + 8){
    csrc[i] = 0;
    cw[i] = 0.f;
  }
}

// MFMA GEMM, bf16 A (exact): acc += A@Wh + A@Wl  == A @ (fp32ish W).
// BM=64, 256 thr (4 waves), wave wv owns coltiles {wv, wv+4}.
template<bool DUAL>
__global__ __launch_bounds__(256) void k_mm(
    const unsigned short* __restrict__ A, const unsigned short* __restrict__ wsplit,
    int mat0, int mat1,
    const float* __restrict__ b0, const float* __restrict__ b1,
    const float* __restrict__ dinv,
    unsigned short* __restrict__ O0b, unsigned short* __restrict__ O1b, int n)
{
  __shared__ unsigned short ash[4][2048];  // [ks][mt(4)][kg(4)][r(16)][j(8)]
  int tid = threadIdx.x;
  int lane = tid & 63;
  int wv = tid >> 6;            // 0..3
  int n0 = blockIdx.x * 64;

  f32x4 acc0[4][2]; f32x4 acc1[DUAL?4:1][DUAL?2:1];
  #pragma unroll
  for (int mt=0; mt<4; ++mt){
    #pragma unroll
    for (int c=0;c<2;c++){ acc0[mt][c]=(f32x4)0.f; if (DUAL) acc1[mt][c]=(f32x4)0.f; }
  }

  int srow = tid >> 2;          // 0..63
  int skg  = tid & 3;
  bool svalid = (n0 + srow) < n;
  const unsigned short* aptr = A + (size_t)(n0 + srow)*HID + skg*8;
  int selem = (srow>>4)*512 + skg*128 + (srow&15)*8;

  #pragma unroll
  for (int ks=0; ks<4; ++ks){
    bf16x8 v = {0,0,0,0,0,0,0,0};
    if (svalid) v = *(const bf16x8*)(aptr + ks*32);
    *(bf16x8*)&ash[ks][selem] = v;
  }
  __syncthreads();

  int flane = ((lane>>4)*128) + ((lane&15)*8);
  int ct0 = wv, ct1 = wv + 4;

  for (int ks=0; ks<4; ++ks){
    bf16x8 ah[4];
    #pragma unroll
    for (int mt=0; mt<4; ++mt) ah[mt] = *(const bf16x8*)&ash[ks][mt*512 + flane];
    {
      size_t wb = (((size_t)(mat0*2)*4 + ks)*8)*1024 + flane;
      bf16x8 wh0 = *(const bf16x8*)&wsplit[wb + (size_t)ct0*1024];
      bf16x8 wl0 = *(const bf16x8*)&wsplit[wb + (size_t)ct0*1024 + 32768];
      bf16x8 wh1 = *(const bf16x8*)&wsplit[wb + (size_t)ct1*1024];
      bf16x8 wl1 = *(const bf16x8*)&wsplit[wb + (size_t)ct1*1024 + 32768];
      #pragma unroll
      for (int mt=0; mt<4; ++mt){
        acc0[mt][0] = __builtin_amdgcn_mfma_f32_16x16x32_bf16(ah[mt], wh0, acc0[mt][0], 0,0,0);
        acc0[mt][0] = __builtin_amdgcn_mfma_f32_16x16x32_bf16(ah[mt], wl0, acc0[mt][0], 0,0,0);
        acc0[mt][1] = __builtin_amdgcn_mfma_f32_16x16x32_bf16(ah[mt], wh1, acc0[mt][1], 0,0,0);
        acc0[mt][1] = __builtin_amdgcn_mfma_f32_16x16x32_bf16(ah[mt], wl1, acc0[mt][1], 0,0,0);
      }
    }
    if (DUAL){
      size_t wb = (((size_t)(mat1*2)*4 + ks)*8)*1024 + flane;
      bf16x8 wh0 = *(const bf16x8*)&wsplit[wb + (size_t)ct0*1024];
      bf16x8 wl0 = *(const bf16x8*)&wsplit[wb + (size_t)ct0*1024 + 32768];
      bf16x8 wh1 = *(const bf16x8*)&wsplit[wb + (size_t)ct1*1024];
      bf16x8 wl1 = *(const bf16x8*)&wsplit[wb + (size_t)ct1*1024 + 32768];
      #pragma unroll
      for (int mt=0; mt<4; ++mt){
        acc1[mt][0] = __builtin_amdgcn_mfma_f32_16x16x32_bf16(ah[mt], wh0, acc1[mt][0], 0,0,0);
        acc1[mt][0] = __builtin_amdgcn_mfma_f32_16x16x32_bf16(ah[mt], wl0, acc1[mt][0], 0,0,0);
        acc1[mt][1] = __builtin_amdgcn_mfma_f32_16x16x32_bf16(ah[mt], wh1, acc1[mt][1], 0,0,0);
        acc1[mt][1] = __builtin_amdgcn_mfma_f32_16x16x32_bf16(ah[mt], wl1, acc1[mt][1], 0,0,0);
      }
    }
  }

  // epilogue: D[i][c]: i=(lane>>4)*4+r, c=lane&15
  int cA = ct0*16 + (lane&15);
  int cB = ct1*16 + (lane&15);
  float bb0A = b0[cA], bb0B = b0[cB];
  float bb1A = DUAL ? b1[cA] : 0.f;
  float bb1B = DUAL ? b1[cB] : 0.f;
  #pragma unroll
  for (int mt=0; mt<4; ++mt){
    #pragma unroll
    for (int r=0; r<4; ++r){
      int gn = n0 + mt*16 + (lane>>4)*4 + r;
      if (gn >= n) continue;
      float xA = acc0[mt][0][r];
      float xB = acc0[mt][1][r];
      if (DUAL){
        float dn = dinv[gn]; float snm = dn*dn;
        O0b[(size_t)gn*HID + cA] = f2bf(xA);
        O0b[(size_t)gn*HID + cB] = f2bf(xB);
        O1b[(size_t)gn*HID + cA] = f2bf(acc1[mt][0][r] + bb0A + bb1A + xA*snm);
        O1b[(size_t)gn*HID + cB] = f2bf(acc1[mt][1][r] + bb0B + bb1B + xB*snm);
      } else {
        O0b[(size_t)gn*HID + cA] = f2bf(eluf(xA + bb0A));
        O0b[(size_t)gn*HID + cB] = f2bf(eluf(xB + bb0B));
      }
    }
  }
}

// one wave per node: AFFINE unconditional csrc/cw loads (wide scalar batching),
// 8 gathers always in flight; tail = weight-masked last batch (arrays padded by 8).
__global__ __launch_bounds__(256) void k_agg(const unsigned* __restrict__ xwb,
    const unsigned* __restrict__ baseb, unsigned* __restrict__ accb,
    const int* __restrict__ rowptr, const int* __restrict__ deg,
    const int* __restrict__ csrc, const float* __restrict__ cw, int n)
{
  int wid = threadIdx.x>>6, lane = threadIdx.x & 63;
  int node = __builtin_amdgcn_readfirstlane(blockIdx.x*4 + wid);
  if (node>=n) return;
  int s = rowptr[node], e = s + deg[node];
  float s0=0.f, s1=0.f;
  for (int p = s; p < e; p += 8){
    int u0=csrc[p],   u1=csrc[p+1], u2=csrc[p+2], u3=csrc[p+3];
    int u4=csrc[p+4], u5=csrc[p+5], u6=csrc[p+6], u7=csrc[p+7];
    float w0=cw[p],   w1=cw[p+1], w2=cw[p+2], w3=cw[p+3];
    float w4=cw[p+4], w5=cw[p+5], w6=cw[p+6], w7=cw[p+7];
    if (p + 8 > e){   // wave-uniform tail mask (loads above stay affine+unconditional)
      w0 = (p+0<e)?w0:0.f; w1 = (p+1<e)?w1:0.f;
      w2 = (p+2<e)?w2:0.f; w3 = (p+3<e)?w3:0.f;
      w4 = (p+4<e)?w4:0.f; w5 = (p+5<e)?w5:0.f;
      w6 = (p+6<e)?w6:0.f; w7 = (p+7<e)?w7:0.f;
    }
    unsigned a0 = xwb[u0*64 + lane];
    unsigned a1 = xwb[u1*64 + lane];
    unsigned a2 = xwb[u2*64 + lane];
    unsigned a3 = xwb[u3*64 + lane];
    unsigned a4 = xwb[u4*64 + lane];
    unsigned a5 = xwb[u5*64 + lane];
    unsigned a6 = xwb[u6*64 + lane];
    unsigned a7 = xwb[u7*64 + lane];
    s0 += w0*bflo(a0); s1 += w0*bfhi(a0);
    s0 += w1*bflo(a1); s1 += w1*bfhi(a1);
    s0 += w2*bflo(a2); s1 += w2*bfhi(a2);
    s0 += w3*bflo(a3); s1 += w3*bfhi(a3);
    s0 += w4*bflo(a4); s1 += w4*bfhi(a4);
    s0 += w5*bflo(a5); s1 += w5*bfhi(a5);
    s0 += w6*bflo(a6); s1 += w6*bfhi(a6);
    s0 += w7*bflo(a7); s1 += w7*bfhi(a7);
  }
  unsigned bb = baseb[(size_t)node*64 + lane];
  float x0 = eluf(bflo(bb) + s0), x1 = eluf(bfhi(bb) + s1);
  unsigned av = accb[(size_t)node*64 + lane];
  accb[(size_t)node*64 + lane] = packbf(bflo(av) + x0, bfhi(av) + x1);
}

static __device__ __forceinline__ int lowerb(const int* a, int nn, int key){
  int lo=0, hi=nn;
  while (lo<hi){ int m=(lo+hi)>>1; if (a[m]<key) lo=m+1; else hi=m; }
  return lo;
}

// deterministic 2-stage pooling, stage 1 (bf16 input)
__global__ __launch_bounds__(128) void k_pool_part(const unsigned short* __restrict__ x,
                                                   const int* __restrict__ batch,
                                                   float* __restrict__ part, int n){
  int g = blockIdx.x / POOL_S, s = blockIdx.x % POOL_S;
  int d = threadIdx.x;
  int lo = lowerb(batch, n, g), hi = lowerb(batch, n, g+1);
  float sum = 0.f;
  for (int r = lo + s; r < hi; r += POOL_S) sum += bf2f(x[(size_t)r*HID + d]);
  part[blockIdx.x*HID + d] = sum;
}

__global__ __launch_bounds__(128) void k_pred(const float* __restrict__ part, const float* __restrict__ W,
                                              const float* __restrict__ b, float* __restrict__ out, int G){
  __shared__ float pr[HID];
  int g = blockIdx.x, o = threadIdx.x;
  float s = 0.f;
  #pragma unroll
  for (int q=0;q<POOL_S;q++) s += part[(g*POOL_S+q)*HID + o];
  pr[o] = s;
  __syncthreads();
  float acc = b[o];
  #pragma unroll 8
  for (int k=0;k<HID;k++) acc += pr[k]*W[k*HID+o];
  out[g*HID+o] = acc*0.1f;
}

extern "C" void kernel_launch(void* const* d_in, const int* in_sizes, int n_in,
                              void* d_out, int out_size, void* d_ws, size_t ws_size,
                              hipStream_t stream)
{
  const int*   x_idx  = (const int*)d_in[0];
  const int*   eidx   = (const int*)d_in[1];
  const int*   batch  = (const int*)d_in[2];
  const float* emb    = (const float*)d_in[3];
  const float* convW  = (const float*)d_in[4];
  const float* convb  = (const float*)d_in[5];
  const float* linW   = (const float*)d_in[6];
  const float* linb   = (const float*)d_in[7];
  const float* mlpW   = (const float*)d_in[8];
  const float* mlpb   = (const float*)d_in[9];
  const float* predW  = (const float*)d_in[10];
  const float* predb  = (const float*)d_in[11];
  float* out = (float*)d_out;
  int N = in_sizes[0];
  int E = in_sizes[1]/2;
  int G = out_size / 128;   // OUT = 128
  int NB = (N + (1<<BSH) - 1) >> BSH;

  char* p = (char*)d_ws;
  auto alloc = [&](size_t bytes)->char*{ char* q = p; p += (bytes + 255) & ~(size_t)255; return q; };
  int*   deg    = (int*)  alloc((size_t)N*4);
  int*   rowptr = (int*)  alloc((size_t)N*4);
  int*   bcnt   = (int*)  alloc((size_t)NB*4);
  int*   bbase  = (int*)  alloc((size_t)NB*4);
  float* dinv   = (float*)alloc((size_t)N*4);
  int*   csrc   = (int*)  alloc((size_t)(E+8)*4);
  float* cw     = (float*)alloc((size_t)(E+8)*4);
  unsigned* epacked = (unsigned*)alloc((size_t)E*4);
  unsigned short* accb  = (unsigned short*)alloc((size_t)N*HID*2);
  unsigned short* xwb   = (unsigned short*)alloc((size_t)N*HID*2);
  unsigned short* baseb = (unsigned short*)alloc((size_t)N*HID*2);
  float* part   = (float*)alloc((size_t)G*POOL_S*HID*4);
  unsigned* bedges = (unsigned*)alloc((size_t)NB*BCAP*4);
  unsigned short* wsplit = (unsigned short*)alloc((size_t)7*2*16384*2);
  if ((size_t)(p - (char*)d_ws) > ws_size) return; // ws too small: leave poison -> loud failure

  const int* src = eidx;
  const int* dst = eidx + E;

  hipMemsetAsync(bcnt, 0, (size_t)NB*4, stream);
  int NBU = (E+2047)/2048;
  int NI  = (N*32+255)/256;
  k_bucket_prep<<<NBU+448+NI,256,0,stream>>>(src, dst, bcnt, bedges, E, NB, NBU,
                                             convW, linW, mlpW, wsplit,
                                             emb, x_idx, accb, N);
  k_scan_bcnt<<<1,1024,0,stream>>>(bcnt, bbase, NB);
  k_csr<<<NB,256,0,stream>>>(bedges, bcnt, bbase, deg, rowptr, dinv, epacked, N);
  k_cw<<<(E+8+255)/256,256,0,stream>>>(epacked, dinv, csrc, cw, E);

  int mblk = (N+63)/64;
  for (int l=0;l<3;l++){
    k_mm<true><<<mblk,256,0,stream>>>(accb, wsplit, l, 3+l,
                                      convb + l*HID, linb + l*HID, dinv,
                                      xwb, baseb, N);
    k_agg<<<(N+3)/4,256,0,stream>>>((const unsigned*)xwb, (const unsigned*)baseb,
                                    (unsigned*)accb, rowptr, deg, csrc, cw, N);
  }
  k_mm<false><<<mblk,256,0,stream>>>(accb, wsplit, 6, 6, mlpb, nullptr, nullptr,
                                     xwb, nullptr, N);
  k_pool_part<<<G*POOL_S,128,0,stream>>>(xwb, batch, part, N);
  k_pred<<<G,128,0,stream>>>(part, predW, predb, out, G);
}